// Round 1
// baseline (502.788 us; speedup 1.0000x reference)
//
#include <hip/hip_runtime.h>

#define Bdim 4
#define T 2048
#define C 1024
#define H 16
#define HD 64
#define SCALE 0.125f

typedef __attribute__((ext_vector_type(8))) short short8;
typedef __attribute__((ext_vector_type(4))) float f32x4;

__device__ inline unsigned short f2bf(float f) {
  unsigned int u = __float_as_uint(f);
  return (unsigned short)((u + 0x7FFFu + ((u >> 16) & 1u)) >> 16);
}
__device__ inline float bf2f(unsigned short s) {
  return __uint_as_float(((unsigned int)s) << 16);
}

// ws layout (bytes)
#define OFF_QS   (0)
#define OFF_KS   (16u*1024u*1024u)
#define OFF_WPB  (32u*1024u*1024u)
#define OFF_PART (34u*1024u*1024u)
#define OFF_KTV  (38u*1024u*1024u)
#define OFF_YPRE (39u*1024u*1024u)

// ---------------- kernel 0: f32 -> bf16 convert (mask folded; scale folded into Q),
// transpose (B,T,H,HD) -> (B,H,T,HD) ----------------
__global__ __launch_bounds__(256) void k_convert_qk(
    const float* __restrict__ queries, const float* __restrict__ keys,
    const float* __restrict__ mask,
    unsigned short* __restrict__ Qs, unsigned short* __restrict__ Ks) {
  int idx = blockIdx.x * 256 + threadIdx.x;   // 1,048,576 threads
  long e = (long)idx * 8;
  int b = (int)(e / ((long)T * C));
  int rem = (int)(e % ((long)T * C));
  int t = rem / C;
  int c = rem % C;
  int h = c >> 6, d = c & 63;
  float m = mask[b * T + t];
  const float4* qp = (const float4*)(queries + e);
  const float4* kp = (const float4*)(keys + e);
  float4 q0 = qp[0], q1 = qp[1];
  float4 k0 = kp[0], k1 = kp[1];
  float qv[8] = {q0.x,q0.y,q0.z,q0.w,q1.x,q1.y,q1.z,q1.w};
  float kv[8] = {k0.x,k0.y,k0.z,k0.w,k1.x,k1.y,k1.z,k1.w};
  unsigned short qo[8], ko[8];
  #pragma unroll
  for (int j = 0; j < 8; ++j) {
    qo[j] = f2bf(qv[j] * m * SCALE);
    ko[j] = f2bf(kv[j] * m);
  }
  long dst = ((long)(b * H + h) * T + t) * HD + d;
  *(short8*)(Qs + dst) = *(const short8*)qo;
  *(short8*)(Ks + dst) = *(const short8*)ko;
}

// ---------------- kernel 0b: Wp f32 -> bf16 ----------------
__global__ __launch_bounds__(256) void k_convert_wp(
    const float* __restrict__ Wp, unsigned short* __restrict__ Wpb) {
  long e = ((long)blockIdx.x * 256 + threadIdx.x) * 8;  // 1M elems
  const float4* wp = (const float4*)(Wp + e);
  float4 w0 = wp[0], w1 = wp[1];
  float wv[8] = {w0.x,w0.y,w0.z,w0.w,w1.x,w1.y,w1.z,w1.w};
  unsigned short wo[8];
  #pragma unroll
  for (int j = 0; j < 8; ++j) wo[j] = f2bf(wv[j]);
  *(short8*)(Wpb + e) = *(const short8*)wo;
}

// ---------------- kernel 1: att = Qs @ Ks^T (bf16 MFMA, no LDS), f32 out ----------------
// grid 16384 x 256; block = 128x128 att tile; 4 waves in 2x2, wave = 64x64.
__global__ __launch_bounds__(256) void k_att(
    const unsigned short* __restrict__ Qs, const unsigned short* __restrict__ Ks,
    float* __restrict__ att) {
  int bid = blockIdx.x;
  int wg = ((bid & 7) << 11) | (bid >> 3);      // XCD swizzle (16384 % 8 == 0)
  int bh = wg >> 8;
  int tile = wg & 255;
  int tm = tile >> 4, tn = tile & 15;
  int tid = threadIdx.x;
  int lane = tid & 63, wid = tid >> 6;
  int wr = wid >> 1, wc = wid & 1;
  int lr = lane & 15, kg = lane >> 4;
  const unsigned short* Q = Qs + (long)bh * T * HD;
  const unsigned short* K = Ks + (long)bh * T * HD;
  int row0 = tm * 128 + wr * 64;
  int col0 = tn * 128 + wc * 64;
  short8 a[4][2], b[4][2];
  #pragma unroll
  for (int i = 0; i < 4; ++i) {
    #pragma unroll
    for (int kk = 0; kk < 2; ++kk) {
      a[i][kk] = *(const short8*)(Q + (long)(row0 + i*16 + lr)*HD + kk*32 + kg*8);
      b[i][kk] = *(const short8*)(K + (long)(col0 + i*16 + lr)*HD + kk*32 + kg*8);
    }
  }
  f32x4 acc[4][4];
  #pragma unroll
  for (int i = 0; i < 4; ++i)
    #pragma unroll
    for (int j = 0; j < 4; ++j)
      acc[i][j] = (f32x4){0.f, 0.f, 0.f, 0.f};
  #pragma unroll
  for (int i = 0; i < 4; ++i) {
    #pragma unroll
    for (int j = 0; j < 4; ++j) {
      acc[i][j] = __builtin_amdgcn_mfma_f32_16x16x32_bf16(a[i][0], b[j][0], acc[i][j], 0, 0, 0);
      acc[i][j] = __builtin_amdgcn_mfma_f32_16x16x32_bf16(a[i][1], b[j][1], acc[i][j], 0, 0, 0);
    }
  }
  float* ob = att + (long)bh * T * T;
  #pragma unroll
  for (int i = 0; i < 4; ++i) {
    #pragma unroll
    for (int r = 0; r < 4; ++r) {
      int row = row0 + i*16 + kg*4 + r;
      float* orow = ob + (long)row * T + col0 + lr;
      #pragma unroll
      for (int j = 0; j < 4; ++j) orow[j*16] = acc[i][j][r];
    }
  }
}

// ---------------- kernel 2: partial KtV[b,h] = sum_t (k*m) outer (v*m), T split 4 ways ----------------
__global__ __launch_bounds__(256) void k_ktv_partial(
    const float* __restrict__ keys, const float* __restrict__ x,
    const float* __restrict__ mask, float* __restrict__ part) {
  int bid = blockIdx.x;          // B*H*4 = 256
  int bh = bid >> 2, p = bid & 3;
  int b = bh >> 4, h = bh & 15;
  __shared__ float ks[16][64];
  __shared__ float vs[16][64];
  int tid = threadIdx.x;
  int ty = tid >> 4, tx = tid & 15;
  float acc[4][4];
  #pragma unroll
  for (int i = 0; i < 4; ++i)
    #pragma unroll
    for (int j = 0; j < 4; ++j) acc[i][j] = 0.f;
  int tbeg = p * 512;
  for (int t0 = tbeg; t0 < tbeg + 512; t0 += 16) {
    __syncthreads();
    for (int e = tid; e < 1024; e += 256) {
      int tt = e >> 6, d = e & 63;
      long gi = ((long)(b * T + t0 + tt)) * C + h * 64 + d;
      float m = mask[b * T + t0 + tt];
      ks[tt][d] = keys[gi] * m;
      vs[tt][d] = x[gi] * m;
    }
    __syncthreads();
    #pragma unroll 4
    for (int tt = 0; tt < 16; ++tt) {
      float ka[4], va[4];
      #pragma unroll
      for (int i = 0; i < 4; ++i) { ka[i] = ks[tt][ty + 16*i]; va[i] = vs[tt][tx + 16*i]; }
      #pragma unroll
      for (int i = 0; i < 4; ++i)
        #pragma unroll
        for (int j = 0; j < 4; ++j) acc[i][j] += ka[i] * va[j];
    }
  }
  float* o = part + (long)bid * 4096;
  #pragma unroll
  for (int i = 0; i < 4; ++i)
    #pragma unroll
    for (int j = 0; j < 4; ++j) o[(ty + 16*i) * 64 + tx + 16*j] = acc[i][j];
}

// ---------------- kernel 2b: reduce 4 partials ----------------
__global__ __launch_bounds__(256) void k_ktv_reduce(
    const float* __restrict__ part, float* __restrict__ ktv) {
  int i = blockIdx.x * 256 + threadIdx.x;  // 262144
  int bh = i >> 12, off = i & 4095;
  const float* pp = part + (long)bh * 4 * 4096 + off;
  ktv[i] = pp[0] + pp[4096] + pp[8192] + pp[12288];
}

// ---------------- kernel 3: y_pre[b,t,:] = Qs[b,h,t,:] @ KtV[b,h]  (bf16 out) ----------------
__global__ __launch_bounds__(256) void k_ypre(
    const unsigned short* __restrict__ Qs, const float* __restrict__ ktv,
    unsigned short* __restrict__ ypre) {
  int blk = blockIdx.x;            // 512
  int b = blk >> 7;
  int t0 = (blk & 127) << 4;
  __shared__ float qsm[16][68];    // padded (stride 64 would 4-way conflict)
  __shared__ float kv[64][64];
  int tid = threadIdx.x;
  int rown = tid >> 4;
  int c0 = (tid & 15) * 4;
  for (int h = 0; h < H; ++h) {
    __syncthreads();
    const unsigned short* qh = Qs + ((long)(b * H + h) * T + t0) * HD;
    for (int e = tid; e < 1024; e += 256) qsm[e >> 6][e & 63] = bf2f(qh[(e >> 6) * HD + (e & 63)]);
    const float* kh = ktv + (b * H + h) * 4096;
    for (int e = tid; e < 4096; e += 256) kv[e >> 6][e & 63] = kh[e];
    __syncthreads();
    float a0 = 0.f, a1 = 0.f, a2 = 0.f, a3 = 0.f;
    #pragma unroll 8
    for (int d1 = 0; d1 < 64; ++d1) {
      float q = qsm[rown][d1];
      a0 += q * kv[d1][c0 + 0];
      a1 += q * kv[d1][c0 + 1];
      a2 += q * kv[d1][c0 + 2];
      a3 += q * kv[d1][c0 + 3];
    }
    unsigned short* yo = ypre + ((long)(b * T + t0 + rown)) * C + h * HD + c0;
    yo[0] = f2bf(a0); yo[1] = f2bf(a1); yo[2] = f2bf(a2); yo[3] = f2bf(a3);
  }
}

// ---------------- kernel 4: y = ypre @ Wp^T + bp (bf16 MFMA, no LDS) ----------------
// M=8192, N=1024, K=1024; 128x128 tiles -> 512 blocks.
__global__ __launch_bounds__(256) void k_proj(
    const unsigned short* __restrict__ A, const unsigned short* __restrict__ Bw,
    const float* __restrict__ bp, float* __restrict__ y) {
  int bid = blockIdx.x;
  int wg = ((bid & 7) << 6) | (bid >> 3);   // XCD swizzle (512 % 8 == 0)
  int tm = wg >> 3, tn = wg & 7;
  int tid = threadIdx.x;
  int lane = tid & 63, wid = tid >> 6;
  int wr = wid >> 1, wc = wid & 1;
  int lr = lane & 15, kg = lane >> 4;
  int row0 = tm * 128 + wr * 64;
  int col0 = tn * 128 + wc * 64;
  f32x4 acc[4][4];
  #pragma unroll
  for (int i = 0; i < 4; ++i)
    #pragma unroll
    for (int j = 0; j < 4; ++j) acc[i][j] = (f32x4){0.f, 0.f, 0.f, 0.f};
  #pragma unroll 4
  for (int k0 = 0; k0 < C; k0 += 32) {
    short8 av[4], bv[4];
    #pragma unroll
    for (int i = 0; i < 4; ++i)
      av[i] = *(const short8*)(A + (long)(row0 + i*16 + lr) * C + k0 + kg*8);
    #pragma unroll
    for (int j = 0; j < 4; ++j)
      bv[j] = *(const short8*)(Bw + (long)(col0 + j*16 + lr) * C + k0 + kg*8);
    #pragma unroll
    for (int i = 0; i < 4; ++i)
      #pragma unroll
      for (int j = 0; j < 4; ++j)
        acc[i][j] = __builtin_amdgcn_mfma_f32_16x16x32_bf16(av[i], bv[j], acc[i][j], 0, 0, 0);
  }
  #pragma unroll
  for (int i = 0; i < 4; ++i) {
    #pragma unroll
    for (int r = 0; r < 4; ++r) {
      int row = row0 + i*16 + kg*4 + r;
      float* orow = y + (long)row * C;
      #pragma unroll
      for (int j = 0; j < 4; ++j) {
        int col = col0 + j*16 + lr;
        orow[col] = acc[i][j][r] + bp[col];
      }
    }
  }
}

extern "C" void kernel_launch(void* const* d_in, const int* in_sizes, int n_in,
                              void* d_out, int out_size, void* d_ws, size_t ws_size,
                              hipStream_t stream) {
  const float* x       = (const float*)d_in[0];
  const float* keys    = (const float*)d_in[1];
  const float* queries = (const float*)d_in[2];
  const float* mask    = (const float*)d_in[3];
  const float* Wp      = (const float*)d_in[4];
  const float* bp      = (const float*)d_in[5];

  float* y   = (float*)d_out;
  float* att = (float*)d_out + (long)Bdim * T * C;

  char* ws = (char*)d_ws;
  unsigned short* Qs   = (unsigned short*)(ws + OFF_QS);
  unsigned short* Ks   = (unsigned short*)(ws + OFF_KS);
  unsigned short* Wpb  = (unsigned short*)(ws + OFF_WPB);
  float* part          = (float*)(ws + OFF_PART);
  float* ktv           = (float*)(ws + OFF_KTV);
  unsigned short* ypre = (unsigned short*)(ws + OFF_YPRE);

  k_convert_qk<<<dim3(4096), dim3(256), 0, stream>>>(queries, keys, mask, Qs, Ks);
  k_convert_wp<<<dim3(512), dim3(256), 0, stream>>>(Wp, Wpb);
  k_att<<<dim3(16384), dim3(256), 0, stream>>>(Qs, Ks, att);
  k_ktv_partial<<<dim3(256), dim3(256), 0, stream>>>(keys, x, mask, part);
  k_ktv_reduce<<<dim3(1024), dim3(256), 0, stream>>>(part, ktv);
  k_ypre<<<dim3(512), dim3(256), 0, stream>>>(Qs, ktv, ypre);
  k_proj<<<dim3(512), dim3(256), 0, stream>>>(ypre, Wpb, bp, y);
}

// Round 2
// 433.475 us; speedup vs baseline: 1.1599x; 1.1599x over previous
//
#include <hip/hip_runtime.h>

#define Bdim 4
#define T 2048
#define C 1024
#define H 16
#define HD 64
#define SCALE 0.125f

typedef __attribute__((ext_vector_type(8))) short short8;
typedef __attribute__((ext_vector_type(4))) float f32x4;

__device__ inline unsigned short f2bf(float f) {
  unsigned int u = __float_as_uint(f);
  return (unsigned short)((u + 0x7FFFu + ((u >> 16) & 1u)) >> 16);
}

// ws layout (bytes)
#define OFF_QS   (0u)                    // 16 MiB  bf16 Q (B,H,T,HD), scale+mask folded
#define OFF_KS   (16u*1024u*1024u)       // 16 MiB  bf16 K (B,H,T,HD), mask folded
#define OFF_PART (32u*1024u*1024u)       // 8 MiB   KtV partials (512 x 4096 f32)
#define OFF_KTV  (40u*1024u*1024u)       // 1 MiB   KtV (B*H x 64 x 64 f32)
#define OFF_GT   (41u*1024u*1024u)       // 8 MiB   bf16 G^T (B, N=1024, K=1024)

// ---------------- kernel 0: f32 -> bf16 convert (mask folded; scale folded into Q),
// transpose (B,T,H,HD) -> (B,H,T,HD) ----------------
__global__ __launch_bounds__(256) void k_convert_qk(
    const float* __restrict__ queries, const float* __restrict__ keys,
    const float* __restrict__ mask,
    unsigned short* __restrict__ Qs, unsigned short* __restrict__ Ks) {
  int idx = blockIdx.x * 256 + threadIdx.x;
  long e = (long)idx * 8;
  int b = (int)(e / ((long)T * C));
  int rem = (int)(e % ((long)T * C));
  int t = rem / C;
  int c = rem % C;
  int h = c >> 6, d = c & 63;
  float m = mask[b * T + t];
  const float4* qp = (const float4*)(queries + e);
  const float4* kp = (const float4*)(keys + e);
  float4 q0 = qp[0], q1 = qp[1];
  float4 k0 = kp[0], k1 = kp[1];
  float qv[8] = {q0.x,q0.y,q0.z,q0.w,q1.x,q1.y,q1.z,q1.w};
  float kv[8] = {k0.x,k0.y,k0.z,k0.w,k1.x,k1.y,k1.z,k1.w};
  unsigned short qo[8], ko[8];
  #pragma unroll
  for (int j = 0; j < 8; ++j) {
    qo[j] = f2bf(qv[j] * m * SCALE);
    ko[j] = f2bf(kv[j] * m);
  }
  long dst = ((long)(b * H + h) * T + t) * HD + d;
  *(short8*)(Qs + dst) = *(const short8*)qo;
  *(short8*)(Ks + dst) = *(const short8*)ko;
}

// ---------------- kernel 1: att = Qs @ Ks^T (bf16 MFMA, no LDS), f32 out ----------------
// Swapped-operand MFMA: lane holds 4 CONSECUTIVE att columns -> dwordx4 nt stores.
__global__ __launch_bounds__(256) void k_att(
    const unsigned short* __restrict__ Qs, const unsigned short* __restrict__ Ks,
    float* __restrict__ att) {
  int bid = blockIdx.x;
  int wg = ((bid & 7) << 11) | (bid >> 3);      // XCD swizzle (16384 % 8 == 0)
  int bh = wg >> 8;
  int tile = wg & 255;
  int tm = tile >> 4, tn = tile & 15;
  int tid = threadIdx.x;
  int lane = tid & 63, wid = tid >> 6;
  int wr = wid >> 1, wc = wid & 1;
  int lr = lane & 15, kg = lane >> 4;
  const unsigned short* Q = Qs + (long)bh * T * HD;
  const unsigned short* K = Ks + (long)bh * T * HD;
  int row0 = tm * 128 + wr * 64;   // q rows
  int col0 = tn * 128 + wc * 64;   // k cols
  short8 a[4][2], b[4][2];
  #pragma unroll
  for (int i = 0; i < 4; ++i) {
    #pragma unroll
    for (int kk = 0; kk < 2; ++kk) {
      a[i][kk] = *(const short8*)(Q + (long)(row0 + i*16 + lr)*HD + kk*32 + kg*8);
      b[i][kk] = *(const short8*)(K + (long)(col0 + i*16 + lr)*HD + kk*32 + kg*8);
    }
  }
  f32x4 acc[4][4];
  #pragma unroll
  for (int i = 0; i < 4; ++i)
    #pragma unroll
    for (int j = 0; j < 4; ++j)
      acc[i][j] = (f32x4){0.f, 0.f, 0.f, 0.f};
  #pragma unroll
  for (int i = 0; i < 4; ++i) {
    #pragma unroll
    for (int j = 0; j < 4; ++j) {
      // swapped: D[krow][qrow] -> lane (lr,kg) reg r = att[q=i*16+lr][k=j*16+kg*4+r]
      acc[i][j] = __builtin_amdgcn_mfma_f32_16x16x32_bf16(b[j][0], a[i][0], acc[i][j], 0, 0, 0);
      acc[i][j] = __builtin_amdgcn_mfma_f32_16x16x32_bf16(b[j][1], a[i][1], acc[i][j], 0, 0, 0);
    }
  }
  float* ob = att + (long)bh * T * T;
  #pragma unroll
  for (int i = 0; i < 4; ++i) {
    long rbase = (long)(row0 + i*16 + lr) * T + col0 + kg*4;
    #pragma unroll
    for (int j = 0; j < 4; ++j) {
      __builtin_nontemporal_store(acc[i][j], (f32x4*)(ob + rbase + j*16));
    }
  }
}

// ---------------- kernel 2: partial KtV[b,h] = sum_t (k*m) outer (v*m), T split 8 ways ----------------
__global__ __launch_bounds__(256) void k_ktv_partial(
    const float* __restrict__ keys, const float* __restrict__ x,
    const float* __restrict__ mask, float* __restrict__ part) {
  int bid = blockIdx.x;          // B*H*8 = 512
  int bh = bid >> 3, p = bid & 7;
  int b = bh >> 4, h = bh & 15;
  __shared__ float ks[16][64];
  __shared__ float vs[16][64];
  int tid = threadIdx.x;
  int ty = tid >> 4, tx = tid & 15;
  float acc[4][4];
  #pragma unroll
  for (int i = 0; i < 4; ++i)
    #pragma unroll
    for (int j = 0; j < 4; ++j) acc[i][j] = 0.f;
  int tbeg = p * 256;
  for (int t0 = tbeg; t0 < tbeg + 256; t0 += 16) {
    __syncthreads();
    for (int e = tid; e < 1024; e += 256) {
      int tt = e >> 6, d = e & 63;
      long gi = ((long)(b * T + t0 + tt)) * C + h * 64 + d;
      float m = mask[b * T + t0 + tt];
      ks[tt][d] = keys[gi] * m;
      vs[tt][d] = x[gi] * m;
    }
    __syncthreads();
    #pragma unroll 4
    for (int tt = 0; tt < 16; ++tt) {
      float ka[4], va[4];
      #pragma unroll
      for (int i = 0; i < 4; ++i) { ka[i] = ks[tt][ty + 16*i]; va[i] = vs[tt][tx + 16*i]; }
      #pragma unroll
      for (int i = 0; i < 4; ++i)
        #pragma unroll
        for (int j = 0; j < 4; ++j) acc[i][j] += ka[i] * va[j];
    }
  }
  float* o = part + (long)bid * 4096;
  #pragma unroll
  for (int i = 0; i < 4; ++i)
    #pragma unroll
    for (int j = 0; j < 4; ++j) o[(ty + 16*i) * 64 + tx + 16*j] = acc[i][j];
}

// ---------------- kernel 2b: reduce 8 partials ----------------
__global__ __launch_bounds__(256) void k_ktv_reduce(
    const float* __restrict__ part, float* __restrict__ ktv) {
  int i = blockIdx.x * 256 + threadIdx.x;  // 262144
  int bh = i >> 12, off = i & 4095;
  const float* pp = part + (long)bh * 8 * 4096 + off;
  float s = 0.f;
  #pragma unroll
  for (int p = 0; p < 8; ++p) s += pp[p * 4096];
  ktv[i] = s;
}

// ---------------- kernel 3: Gt[b][n][h*64+d] = sum_e KtV[b,h][d][e] * Wp[n][h*64+e] (bf16 out) ----------------
__global__ __launch_bounds__(256) void k_gt(
    const float* __restrict__ ktv, const float* __restrict__ Wp,
    unsigned short* __restrict__ Gt) {
  int bid = blockIdx.x;            // B*H*16 = 1024
  int b = bid >> 8;
  int h = (bid >> 4) & 15;
  int n0 = (bid & 15) * 64;
  __shared__ float kv[64][64];     // KtV[d][e] (broadcast reads)
  __shared__ float wp[64][65];     // Wp[n][e], padded
  int tid = threadIdx.x;
  for (int e = tid; e < 4096; e += 256) {
    kv[e >> 6][e & 63] = ktv[((b * H + h) << 12) + e];
    wp[e >> 6][e & 63] = Wp[(long)(n0 + (e >> 6)) * C + h * 64 + (e & 63)];
  }
  __syncthreads();
  int nl = tid & 63, dg = tid >> 6;
  float s[16];
  #pragma unroll
  for (int dd = 0; dd < 16; ++dd) s[dd] = 0.f;
  for (int e = 0; e < 64; ++e) {
    float w = wp[nl][e];
    #pragma unroll
    for (int dd = 0; dd < 16; ++dd)
      s[dd] += kv[dg * 16 + dd][e] * w;
  }
  unsigned short o[16];
  #pragma unroll
  for (int dd = 0; dd < 16; ++dd) o[dd] = f2bf(s[dd]);
  unsigned short* dst = Gt + ((long)(b * C + n0 + nl)) * C + h * 64 + dg * 16;
  *(short8*)dst = *(const short8*)o;
  *(short8*)(dst + 8) = *(const short8*)(o + 8);
}

// ---------------- kernel 4: y[b] = Qflat[b] @ Gt[b]^T + bp (bf16 MFMA, no LDS) ----------------
// Qflat[b][t][h*64+d] = Qs[b,h,t,d]. M=2048, N=1024, K=1024 per b; 128x128 tiles.
__global__ __launch_bounds__(256) void k_out(
    const unsigned short* __restrict__ Qs, const unsigned short* __restrict__ Gt,
    const float* __restrict__ bp, float* __restrict__ y) {
  int bid = blockIdx.x;
  int wg = ((bid & 7) << 6) | (bid >> 3);   // XCD swizzle (512 % 8 == 0)
  int b = wg >> 7;
  int tile = wg & 127;                      // 16 row-tiles x 8 col-tiles
  int tm = tile >> 3, tn = tile & 7;
  int tid = threadIdx.x;
  int lane = tid & 63, wid = tid >> 6;
  int wr = wid >> 1, wc = wid & 1;
  int lr = lane & 15, kg = lane >> 4;
  int row0 = tm * 128 + wr * 64;   // t
  int col0 = tn * 128 + wc * 64;   // n
  f32x4 acc[4][4];
  #pragma unroll
  for (int i = 0; i < 4; ++i)
    #pragma unroll
    for (int j = 0; j < 4; ++j) acc[i][j] = (f32x4){0.f, 0.f, 0.f, 0.f};
  #pragma unroll 4
  for (int k0 = 0; k0 < C; k0 += 32) {
    int h = k0 >> 6;
    int off = (k0 & 63) + kg * 8;
    const unsigned short* qb = Qs + (long)(b * H + h) * T * HD;
    const unsigned short* gb = Gt + (long)b * C * C + k0 + kg * 8;
    short8 av[4], bv[4];
    #pragma unroll
    for (int i = 0; i < 4; ++i)
      av[i] = *(const short8*)(qb + (long)(row0 + i*16 + lr) * HD + off);
    #pragma unroll
    for (int j = 0; j < 4; ++j)
      bv[j] = *(const short8*)(gb + (long)(col0 + j*16 + lr) * C);
    #pragma unroll
    for (int i = 0; i < 4; ++i)
      #pragma unroll
      for (int j = 0; j < 4; ++j)
        acc[i][j] = __builtin_amdgcn_mfma_f32_16x16x32_bf16(bv[j], av[i], acc[i][j], 0, 0, 0);
  }
  #pragma unroll
  for (int i = 0; i < 4; ++i) {
    int row = row0 + i*16 + lr;
    float* yrow = y + (long)(b * T + row) * C;
    #pragma unroll
    for (int j = 0; j < 4; ++j) {
      int col = col0 + j*16 + kg*4;
      f32x4 res = acc[i][j] + *(const f32x4*)(bp + col);
      *(f32x4*)(yrow + col) = res;
    }
  }
}

extern "C" void kernel_launch(void* const* d_in, const int* in_sizes, int n_in,
                              void* d_out, int out_size, void* d_ws, size_t ws_size,
                              hipStream_t stream) {
  const float* x       = (const float*)d_in[0];
  const float* keys    = (const float*)d_in[1];
  const float* queries = (const float*)d_in[2];
  const float* mask    = (const float*)d_in[3];
  const float* Wp      = (const float*)d_in[4];
  const float* bp      = (const float*)d_in[5];

  float* y   = (float*)d_out;
  float* att = (float*)d_out + (long)Bdim * T * C;

  char* ws = (char*)d_ws;
  unsigned short* Qs   = (unsigned short*)(ws + OFF_QS);
  unsigned short* Ks   = (unsigned short*)(ws + OFF_KS);
  float* part          = (float*)(ws + OFF_PART);
  float* ktv           = (float*)(ws + OFF_KTV);
  unsigned short* Gt   = (unsigned short*)(ws + OFF_GT);

  k_convert_qk<<<dim3(4096), dim3(256), 0, stream>>>(queries, keys, mask, Qs, Ks);
  k_ktv_partial<<<dim3(512), dim3(256), 0, stream>>>(keys, x, mask, part);
  k_att<<<dim3(16384), dim3(256), 0, stream>>>(Qs, Ks, att);
  k_ktv_reduce<<<dim3(1024), dim3(256), 0, stream>>>(part, ktv);
  k_gt<<<dim3(1024), dim3(256), 0, stream>>>(ktv, Wp, Gt);
  k_out<<<dim3(512), dim3(256), 0, stream>>>(Qs, Gt, bp, y);
}

// Round 3
// 420.463 us; speedup vs baseline: 1.1958x; 1.0309x over previous
//
#include <hip/hip_runtime.h>

#define Bdim 4
#define T 2048
#define C 1024
#define H 16
#define HD 64
#define SCALE 0.125f

typedef __attribute__((ext_vector_type(8))) short short8;
typedef __attribute__((ext_vector_type(4))) float f32x4;

__device__ inline unsigned short f2bf(float f) {
  unsigned int u = __float_as_uint(f);
  return (unsigned short)((u + 0x7FFFu + ((u >> 16) & 1u)) >> 16);
}

// ws layout (bytes) — total 49 MiB
#define OFF_QS   (0u)                    // 16 MiB  bf16 Q (B,H,T,HD), scale+mask folded
#define OFF_KS   (16u*1024u*1024u)       // 16 MiB  bf16 K (B,H,T,HD), mask folded
#define OFF_PART (32u*1024u*1024u)       // 16 MiB  KtV partials (1024 x 4096 f32)
#define OFF_GT   (32u*1024u*1024u)       // 8 MiB   bf16 G^T — ALIASES PART (part dead by k_gt)
#define OFF_KTV  (48u*1024u*1024u)       // 1 MiB   KtV (B*H x 64 x 64 f32)

// ---------------- kernel 0: f32 -> bf16 convert (mask folded; scale folded into Q),
// transpose (B,T,H,HD) -> (B,H,T,HD) ----------------
__global__ __launch_bounds__(256) void k_convert_qk(
    const float* __restrict__ queries, const float* __restrict__ keys,
    const float* __restrict__ mask,
    unsigned short* __restrict__ Qs, unsigned short* __restrict__ Ks) {
  int idx = blockIdx.x * 256 + threadIdx.x;
  long e = (long)idx * 8;
  int b = (int)(e / ((long)T * C));
  int rem = (int)(e % ((long)T * C));
  int t = rem / C;
  int c = rem % C;
  int h = c >> 6, d = c & 63;
  float m = mask[b * T + t];
  const float4* qp = (const float4*)(queries + e);
  const float4* kp = (const float4*)(keys + e);
  float4 q0 = qp[0], q1 = qp[1];
  float4 k0 = kp[0], k1 = kp[1];
  float qv[8] = {q0.x,q0.y,q0.z,q0.w,q1.x,q1.y,q1.z,q1.w};
  float kv[8] = {k0.x,k0.y,k0.z,k0.w,k1.x,k1.y,k1.z,k1.w};
  unsigned short qo[8], ko[8];
  #pragma unroll
  for (int j = 0; j < 8; ++j) {
    qo[j] = f2bf(qv[j] * m * SCALE);
    ko[j] = f2bf(kv[j] * m);
  }
  long dst = ((long)(b * H + h) * T + t) * HD + d;
  *(short8*)(Qs + dst) = *(const short8*)qo;
  *(short8*)(Ks + dst) = *(const short8*)ko;
}

// ---------------- kernel 1: att = Qs @ Ks^T (bf16 MFMA, no LDS), f32 out ----------------
// K=64 is consumed in 2 MFMAs per tile -> transient accumulator, store immediately.
// Swapped-operand MFMA: lane holds 4 CONSECUTIVE att columns -> dwordx4 stores.
__global__ __launch_bounds__(256) void k_att(
    const unsigned short* __restrict__ Qs, const unsigned short* __restrict__ Ks,
    float* __restrict__ att) {
  int bid = blockIdx.x;
  int wg = ((bid & 7) << 11) | (bid >> 3);      // XCD swizzle (16384 % 8 == 0)
  int bh = wg >> 8;
  int tile = wg & 255;
  int tm = tile >> 4, tn = tile & 15;
  int tid = threadIdx.x;
  int lane = tid & 63, wid = tid >> 6;
  int wr = wid >> 1, wc = wid & 1;
  int lr = lane & 15, kg = lane >> 4;
  const unsigned short* Q = Qs + (long)bh * T * HD;
  const unsigned short* K = Ks + (long)bh * T * HD;
  int row0 = tm * 128 + wr * 64;   // q rows
  int col0 = tn * 128 + wc * 64;   // k cols
  short8 a[4][2], b[4][2];
  #pragma unroll
  for (int i = 0; i < 4; ++i) {
    #pragma unroll
    for (int kk = 0; kk < 2; ++kk) {
      a[i][kk] = *(const short8*)(Q + (long)(row0 + i*16 + lr)*HD + kk*32 + kg*8);
      b[i][kk] = *(const short8*)(K + (long)(col0 + i*16 + lr)*HD + kk*32 + kg*8);
    }
  }
  float* ob = att + (long)bh * T * T;
  #pragma unroll
  for (int i = 0; i < 4; ++i) {
    long rbase = (long)(row0 + i*16 + lr) * T + col0 + kg*4;
    #pragma unroll
    for (int j = 0; j < 4; ++j) {
      f32x4 acc = (f32x4){0.f, 0.f, 0.f, 0.f};
      acc = __builtin_amdgcn_mfma_f32_16x16x32_bf16(b[j][0], a[i][0], acc, 0, 0, 0);
      acc = __builtin_amdgcn_mfma_f32_16x16x32_bf16(b[j][1], a[i][1], acc, 0, 0, 0);
      *(f32x4*)(ob + rbase + j*16) = acc;
    }
  }
}

// ---------------- kernel 2: partial KtV[b,h] = sum_t (k*m) outer (v*m), T split 16 ways ----------------
__global__ __launch_bounds__(256) void k_ktv_partial(
    const float* __restrict__ keys, const float* __restrict__ x,
    const float* __restrict__ mask, float* __restrict__ part) {
  int bid = blockIdx.x;          // B*H*16 = 1024
  int bh = bid >> 4, p = bid & 15;
  int b = bh >> 4, h = bh & 15;
  __shared__ float ks[16][64];
  __shared__ float vs[16][64];
  int tid = threadIdx.x;
  int ty = tid >> 4, tx = tid & 15;
  float acc[4][4];
  #pragma unroll
  for (int i = 0; i < 4; ++i)
    #pragma unroll
    for (int j = 0; j < 4; ++j) acc[i][j] = 0.f;
  int tbeg = p * 128;
  for (int t0 = tbeg; t0 < tbeg + 128; t0 += 16) {
    __syncthreads();
    for (int e = tid; e < 1024; e += 256) {
      int tt = e >> 6, d = e & 63;
      long gi = ((long)(b * T + t0 + tt)) * C + h * 64 + d;
      float m = mask[b * T + t0 + tt];
      ks[tt][d] = keys[gi] * m;
      vs[tt][d] = x[gi] * m;
    }
    __syncthreads();
    #pragma unroll 4
    for (int tt = 0; tt < 16; ++tt) {
      float ka[4], va[4];
      #pragma unroll
      for (int i = 0; i < 4; ++i) { ka[i] = ks[tt][ty + 16*i]; va[i] = vs[tt][tx + 16*i]; }
      #pragma unroll
      for (int i = 0; i < 4; ++i)
        #pragma unroll
        for (int j = 0; j < 4; ++j) acc[i][j] += ka[i] * va[j];
    }
  }
  float* o = part + (long)bid * 4096;
  #pragma unroll
  for (int i = 0; i < 4; ++i)
    #pragma unroll
    for (int j = 0; j < 4; ++j) o[(ty + 16*i) * 64 + tx + 16*j] = acc[i][j];
}

// ---------------- kernel 2b: reduce 16 partials ----------------
__global__ __launch_bounds__(256) void k_ktv_reduce(
    const float* __restrict__ part, float* __restrict__ ktv) {
  int i = blockIdx.x * 256 + threadIdx.x;  // 262144
  int bh = i >> 12, off = i & 4095;
  const float* pp = part + ((long)bh << 16) + off;
  float s = 0.f;
  #pragma unroll
  for (int p = 0; p < 16; ++p) s += pp[p * 4096];
  ktv[i] = s;
}

// ---------------- kernel 3: Gt[b][n][h*64+d] = sum_e KtV[b,h][d][e] * Wp[n][h*64+e] (bf16 out) ----------------
__global__ __launch_bounds__(256) void k_gt(
    const float* __restrict__ ktv, const float* __restrict__ Wp,
    unsigned short* __restrict__ Gt) {
  int bid = blockIdx.x;            // B*H*16 = 1024
  int b = bid >> 8;
  int h = (bid >> 4) & 15;
  int n0 = (bid & 15) * 64;
  __shared__ float kv[64][64];     // KtV[d][e] (broadcast reads)
  __shared__ float wp[64][65];     // Wp[n][e], padded
  int tid = threadIdx.x;
  for (int e = tid; e < 4096; e += 256) {
    kv[e >> 6][e & 63] = ktv[((b * H + h) << 12) + e];
    wp[e >> 6][e & 63] = Wp[(long)(n0 + (e >> 6)) * C + h * 64 + (e & 63)];
  }
  __syncthreads();
  int nl = tid & 63, dg = tid >> 6;
  float s[16];
  #pragma unroll
  for (int dd = 0; dd < 16; ++dd) s[dd] = 0.f;
  for (int e = 0; e < 64; ++e) {
    float w = wp[nl][e];
    #pragma unroll
    for (int dd = 0; dd < 16; ++dd)
      s[dd] += kv[dg * 16 + dd][e] * w;
  }
  unsigned short o[16];
  #pragma unroll
  for (int dd = 0; dd < 16; ++dd) o[dd] = f2bf(s[dd]);
  unsigned short* dst = Gt + ((long)(b * C + n0 + nl)) * C + h * 64 + dg * 16;
  *(short8*)dst = *(const short8*)o;
  *(short8*)(dst + 8) = *(const short8*)(o + 8);
}

// ---------------- kernel 4: y[b] = Qflat[b] @ Gt[b]^T + bp (bf16 MFMA, no LDS) ----------------
// Qflat[b][t][h*64+d] = Qs[b,h,t,d]. M=2048, N=1024, K=1024 per b; 128x128 tiles.
__global__ __launch_bounds__(256) void k_out(
    const unsigned short* __restrict__ Qs, const unsigned short* __restrict__ Gt,
    const float* __restrict__ bp, float* __restrict__ y) {
  int bid = blockIdx.x;
  int wg = ((bid & 7) << 6) | (bid >> 3);   // XCD swizzle (512 % 8 == 0)
  int b = wg >> 7;
  int tile = wg & 127;                      // 16 row-tiles x 8 col-tiles
  int tm = tile >> 3, tn = tile & 7;
  int tid = threadIdx.x;
  int lane = tid & 63, wid = tid >> 6;
  int wr = wid >> 1, wc = wid & 1;
  int lr = lane & 15, kg = lane >> 4;
  int row0 = tm * 128 + wr * 64;   // t
  int col0 = tn * 128 + wc * 64;   // n
  f32x4 acc[4][4];
  #pragma unroll
  for (int i = 0; i < 4; ++i)
    #pragma unroll
    for (int j = 0; j < 4; ++j) acc[i][j] = (f32x4){0.f, 0.f, 0.f, 0.f};
  #pragma unroll 4
  for (int k0 = 0; k0 < C; k0 += 32) {
    int h = k0 >> 6;
    int off = (k0 & 63) + kg * 8;
    const unsigned short* qb = Qs + (long)(b * H + h) * T * HD;
    const unsigned short* gb = Gt + (long)b * C * C + k0 + kg * 8;
    short8 av[4], bv[4];
    #pragma unroll
    for (int i = 0; i < 4; ++i)
      av[i] = *(const short8*)(qb + (long)(row0 + i*16 + lr) * HD + off);
    #pragma unroll
    for (int j = 0; j < 4; ++j)
      bv[j] = *(const short8*)(gb + (long)(col0 + j*16 + lr) * C);
    #pragma unroll
    for (int i = 0; i < 4; ++i)
      #pragma unroll
      for (int j = 0; j < 4; ++j)
        acc[i][j] = __builtin_amdgcn_mfma_f32_16x16x32_bf16(bv[j], av[i], acc[i][j], 0, 0, 0);
  }
  #pragma unroll
  for (int i = 0; i < 4; ++i) {
    int row = row0 + i*16 + lr;
    float* yrow = y + (long)(b * T + row) * C;
    #pragma unroll
    for (int j = 0; j < 4; ++j) {
      int col = col0 + j*16 + kg*4;
      f32x4 res = acc[i][j] + *(const f32x4*)(bp + col);
      *(f32x4*)(yrow + col) = res;
    }
  }
}

extern "C" void kernel_launch(void* const* d_in, const int* in_sizes, int n_in,
                              void* d_out, int out_size, void* d_ws, size_t ws_size,
                              hipStream_t stream) {
  const float* x       = (const float*)d_in[0];
  const float* keys    = (const float*)d_in[1];
  const float* queries = (const float*)d_in[2];
  const float* mask    = (const float*)d_in[3];
  const float* Wp      = (const float*)d_in[4];
  const float* bp      = (const float*)d_in[5];

  float* y   = (float*)d_out;
  float* att = (float*)d_out + (long)Bdim * T * C;

  char* ws = (char*)d_ws;
  unsigned short* Qs   = (unsigned short*)(ws + OFF_QS);
  unsigned short* Ks   = (unsigned short*)(ws + OFF_KS);
  float* part          = (float*)(ws + OFF_PART);
  float* ktv           = (float*)(ws + OFF_KTV);
  unsigned short* Gt   = (unsigned short*)(ws + OFF_GT);

  k_convert_qk<<<dim3(4096), dim3(256), 0, stream>>>(queries, keys, mask, Qs, Ks);
  k_ktv_partial<<<dim3(1024), dim3(256), 0, stream>>>(keys, x, mask, part);
  k_att<<<dim3(16384), dim3(256), 0, stream>>>(Qs, Ks, att);
  k_ktv_reduce<<<dim3(1024), dim3(256), 0, stream>>>(part, ktv);
  k_gt<<<dim3(1024), dim3(256), 0, stream>>>(ktv, Wp, Gt);
  k_out<<<dim3(512), dim3(256), 0, stream>>>(Qs, Gt, bp, y);
}